// Round 9
// baseline (60.631 us; speedup 1.0000x reference)
//
#include <hip/hip_runtime.h>

#define NQ 5
#define NL 6
#define NG 4
#define DIM 32
#define PATCH 16

typedef _Float16 half8 __attribute__((ext_vector_type(8)));
typedef float f32x4 __attribute__((ext_vector_type(4)));

// CZ-chain sign: flip amplitude i iff # adjacent set-bit pairs is odd.
__device__ __forceinline__ int flip_par(int i) {
    int p = i & (i >> 1) & 0xF;
    p ^= p >> 2; p ^= p >> 1;
    return p & 1;
}

// Stage 1: M_g[r,i] = weight-circuit operator, rows 0..15 (q0=0 slice).
// 128 threads: thread = (g<<5)|col simulates basis vector e_col. Verified R1-R7.
__global__ void build_M(const float* __restrict__ qp, float* __restrict__ M) {
    const float RV = 0.07957747154594767f; // 0.5/(2*pi): v_sin/v_cos take revolutions
    const int tid = threadIdx.x;
    if (tid >= NG * DIM) return;
    const int g = tid >> 5, col = tid & 31;
    float st[DIM];
    #pragma unroll
    for (int i = 0; i < DIM; ++i) st[i] = (i == col) ? 1.0f : 0.0f;
    #pragma unroll 1
    for (int l = 0; l < NL; ++l) {
        #pragma unroll          // w unrolled: st[] indices stay compile-time
        for (int w = 0; w < NQ; ++w) {
            float h = qp[g*(NL*NQ) + l*NQ + w] * RV;
            float c = __builtin_amdgcn_cosf(h);
            float s = __builtin_amdgcn_sinf(h);
            const int bit = 4 - w, str = 1 << bit;
            #pragma unroll
            for (int p = 0; p < 16; ++p) {
                int lo = ((p >> bit) << (bit + 1)) | (p & (str - 1));
                int hi = lo + str;
                float a0 = st[lo], a1 = st[hi];
                st[lo] = c*a0 - s*a1;
                st[hi] = s*a0 + c*a1;
            }
        }
        if (l != NL - 1) {      // outermost sign layer dies in |.|^2
            #pragma unroll
            for (int i = 0; i < DIM; ++i)
                if (flip_par(i)) st[i] = -st[i];
        }
    }
    #pragma unroll
    for (int r = 0; r < PATCH; ++r)
        M[(g*PATCH + r)*DIM + col] = st[r];
}

// Stage 2: D[slot,batch] = M · base via mfma_f32_16x16x32_f16 (f16 hi/lo
// split, 3 MFMA/tile — verified R7). R8/R9: tb-outer loop + per-wave
// XOR-swizzled LDS staging so global stores are 1 KB contiguous nontemporal
// (full-line, no L2 write-allocate RMW, no partial-line segments).
__global__ __launch_bounds__(256, 4) void qgen7(
        const float* __restrict__ x, const float* __restrict__ M,
        float* __restrict__ out) {
    // 32 KB, wave-private union: relay [8][64] f4 (B-frag gather), then
    // stage [16 batches][16 slots] f4 (swizzled). Same-wave program order
    // separates the two lifetimes -> no barrier anywhere in the kernel.
    __shared__ __align__(16) f32x4 smem[4][512];

    const int t = threadIdx.x;
    const int wid = t >> 6, lane = t & 63;
    const int l15 = lane & 15, kg = lane >> 4;
    const int b0 = (blockIdx.x * 4 + wid) * 64;
    f32x4* relay = smem[wid];
    f32x4* stage = smem[wid];

    // ---- A-fragments: M rows, f16 split, loaded once (wave-uniform, L2-hot)
    half8 MhA[NG], MlA[NG];
    #pragma unroll
    for (int g = 0; g < NG; ++g) {
        const float* mp = M + (g * PATCH + l15) * DIM + kg * 8;
        float m8[8];
        *(f32x4*)&m8[0] = *(const f32x4*)&mp[0];
        *(f32x4*)&m8[4] = *(const f32x4*)&mp[4];
        half8 h, lo;
        #pragma unroll
        for (int e = 0; e < 8; ++e) {
            _Float16 hh = (_Float16)m8[e];
            h[e]  = hh;
            lo[e] = (_Float16)(m8[e] - (float)hh);
        }
        MhA[g] = h; MlA[g] = lo;
    }

    // ---- per-lane trig + product state (lane = batch b0+lane). Verified R1-R7.
    const float RV = 0.07957747154594767f;
    float cn[NQ], sn[NQ];
    const float* xp = x + (size_t)(b0 + lane) * NQ;
    #pragma unroll
    for (int w = 0; w < NQ; ++w) {
        float h = xp[w] * RV;
        cn[w] = __builtin_amdgcn_cosf(h);
        sn[w] = __builtin_amdgcn_sinf(h);
    }
    float base[DIM];
    base[0] = cn[0]; base[1] = sn[0];
    #pragma unroll
    for (int w = 1; w < NQ; ++w) {
        #pragma unroll
        for (int j = (1 << w) - 1; j >= 0; --j) {
            float v = base[j];
            base[2*j + 1] = v * sn[w];
            base[2*j]     = v * cn[w];
        }
    }

    // ---- relay base -> B-fragment order (same-wave RAW; wave-private slice)
    #pragma unroll
    for (int q = 0; q < 8; ++q)
        relay[q * 64 + lane] = *(f32x4*)&base[q * 4];

    half8 BhF[4], BlF[4];
    #pragma unroll
    for (int tb = 0; tb < 4; ++tb) {
        f32x4 r0 = relay[(kg*2 + 0) * 64 + tb*16 + l15];
        f32x4 r1 = relay[(kg*2 + 1) * 64 + tb*16 + l15];
        float b8[8] = {r0[0], r0[1], r0[2], r0[3], r1[0], r1[1], r1[2], r1[3]};
        half8 h, lo;
        #pragma unroll
        for (int e = 0; e < 8; ++e) {
            _Float16 hh = (_Float16)b8[e];
            h[e]  = hh;
            lo[e] = (_Float16)(b8[e] - (float)hh);
        }
        BhF[tb] = h; BlF[tb] = lo;
    }

    // ---- main: tb outer. Per tb: 4 gens x 3 MFMA -> scaled p into swizzled
    // stage -> 4 x 1KB contiguous nontemporal stores. All indices static.
    f32x4* ob4 = (f32x4*)(out + (size_t)b0 * 64);
    #pragma unroll 1
    for (int tb = 0; tb < 4; ++tb) {
        #pragma unroll
        for (int g = 0; g < NG; ++g) {
            f32x4 acc = {0.f, 0.f, 0.f, 0.f};
            acc = __builtin_amdgcn_mfma_f32_16x16x32_f16(MhA[g], BhF[tb], acc, 0, 0, 0);
            acc = __builtin_amdgcn_mfma_f32_16x16x32_f16(MlA[g], BhF[tb], acc, 0, 0, 0);
            acc = __builtin_amdgcn_mfma_f32_16x16x32_f16(MhA[g], BlF[tb], acc, 0, 0, 0);
            // D layout (m89-verified): reg r = slot kg*4+r, col l15 = batch.
            float p0 = acc[0]*acc[0], p1 = acc[1]*acc[1];
            float p2 = acc[2]*acc[2], p3 = acc[3]*acc[3];
            float mx = fmaxf(fmaxf(p0, p1), fmaxf(p2, p3));
            mx = fmaxf(mx, __shfl_xor(mx, 16, 64));   // combine the 4 kg lanes
            mx = fmaxf(mx, __shfl_xor(mx, 32, 64));
            float inv = __builtin_amdgcn_rcpf(mx);
            // swizzled slab: [batch l15][f4-slot (g*4+kg) ^ l15]
            f32x4 v = {p0*inv, p1*inv, p2*inv, p3*inv};
            stage[l15 * 16 + ((g*4 + kg) ^ l15)] = v;
        }
        // drain: 4 KB contiguous (batches tb*16..tb*16+15, full 256-B rows)
        #pragma unroll
        for (int j = 0; j < 4; ++j) {
            int f  = lane + 64 * j;      // f4 index within the tb region
            int br = f >> 4;             // local batch 0..15
            int sl = f & 15;             // f4 slot within the row
            f32x4 v = stage[br * 16 + (sl ^ br)];
            __builtin_nontemporal_store(v, &ob4[tb * 256 + f]);
        }
    }
}

extern "C" void kernel_launch(void* const* d_in, const int* in_sizes, int n_in,
                              void* d_out, int out_size, void* d_ws, size_t ws_size,
                              hipStream_t stream) {
    const float* x  = (const float*)d_in[0];
    const float* qp = (const float*)d_in[1];
    float* out = (float*)d_out;
    float* M = (float*)d_ws;               // 8 KB scratch
    const int B = in_sizes[0] / NQ;
    build_M<<<1, 128, 0, stream>>>(qp, M);
    qgen7<<<B / 256, 256, 0, stream>>>(x, M, out);
}

// Round 10
// 26.017 us; speedup vs baseline: 2.3304x; 2.3304x over previous
//
#include <hip/hip_runtime.h>

#define NQ 5
#define NL 6
#define NG 4
#define DIM 32
#define PATCH 16

typedef _Float16 half8 __attribute__((ext_vector_type(8)));
typedef float f32x4 __attribute__((ext_vector_type(4)));

// CZ-chain sign: flip amplitude i iff # adjacent set-bit pairs is odd.
__device__ __forceinline__ int flip_par(int i) {
    int p = i & (i >> 1) & 0xF;
    p ^= p >> 2; p ^= p >> 1;
    return p & 1;
}

// Stage 1: M_g[r,i] = weight-circuit operator, rows 0..15 (q0=0 slice).
// 128 threads: thread = (g<<5)|col simulates basis vector e_col. Verified R1-R9.
__global__ void build_M(const float* __restrict__ qp, float* __restrict__ M) {
    const float RV = 0.07957747154594767f; // 0.5/(2*pi): v_sin/v_cos take revolutions
    const int tid = threadIdx.x;
    if (tid >= NG * DIM) return;
    const int g = tid >> 5, col = tid & 31;
    float st[DIM];
    #pragma unroll
    for (int i = 0; i < DIM; ++i) st[i] = (i == col) ? 1.0f : 0.0f;
    #pragma unroll 1
    for (int l = 0; l < NL; ++l) {
        #pragma unroll          // w unrolled: st[] indices stay compile-time
        for (int w = 0; w < NQ; ++w) {
            float h = qp[g*(NL*NQ) + l*NQ + w] * RV;
            float c = __builtin_amdgcn_cosf(h);
            float s = __builtin_amdgcn_sinf(h);
            const int bit = 4 - w, str = 1 << bit;
            #pragma unroll
            for (int p = 0; p < 16; ++p) {
                int lo = ((p >> bit) << (bit + 1)) | (p & (str - 1));
                int hi = lo + str;
                float a0 = st[lo], a1 = st[hi];
                st[lo] = c*a0 - s*a1;
                st[hi] = s*a0 + c*a1;
            }
        }
        if (l != NL - 1) {      // outermost sign layer dies in |.|^2
            #pragma unroll
            for (int i = 0; i < DIM; ++i)
                if (flip_par(i)) st[i] = -st[i];
        }
    }
    #pragma unroll
    for (int r = 0; r < PATCH; ++r)
        M[(g*PATCH + r)*DIM + col] = st[r];
}

// Stage 2: D[slot,batch] = M · base via mfma_f32_16x16x32_f16 (f16 hi/lo
// split, 3 MFMA/tile — verified R7). Staging/swizzle verified R9 (WRITE was
// exactly 64 MB). R10 fix vs R9: tb loop FULLY UNROLLED so BhF[tb]/BlF[tb]
// are compile-time indexed (rule #20 — R9's unroll-1 caused select/scratch
// bloat: ~10k VALU instrs/wave vs ~550 needed); regular stores (full-line
// 1KB/wave-instr contiguous -> L2 write-combining path, known-good 6.3 TB/s).
__global__ __launch_bounds__(256, 4) void qgen8(
        const float* __restrict__ x, const float* __restrict__ M,
        float* __restrict__ out) {
    // 32 KB, wave-private union: relay [8][64] f4 (B-frag gather), then
    // stage [16 batches][16 slots] f4 (XOR-swizzled), reused per tb. Same-wave
    // program order separates lifetimes -> no barrier anywhere in the kernel.
    __shared__ __align__(16) f32x4 smem[4][512];

    const int t = threadIdx.x;
    const int wid = t >> 6, lane = t & 63;
    const int l15 = lane & 15, kg = lane >> 4;
    const int b0 = (blockIdx.x * 4 + wid) * 64;
    f32x4* relay = smem[wid];
    f32x4* stage = smem[wid];

    // ---- A-fragments: M rows, f16 split, loaded once (wave-uniform, L2-hot)
    half8 MhA[NG], MlA[NG];
    #pragma unroll
    for (int g = 0; g < NG; ++g) {
        const float* mp = M + (g * PATCH + l15) * DIM + kg * 8;
        float m8[8];
        *(f32x4*)&m8[0] = *(const f32x4*)&mp[0];
        *(f32x4*)&m8[4] = *(const f32x4*)&mp[4];
        half8 h, lo;
        #pragma unroll
        for (int e = 0; e < 8; ++e) {
            _Float16 hh = (_Float16)m8[e];
            h[e]  = hh;
            lo[e] = (_Float16)(m8[e] - (float)hh);
        }
        MhA[g] = h; MlA[g] = lo;
    }

    // ---- per-lane trig + product state (lane = batch b0+lane). Verified R1-R9.
    const float RV = 0.07957747154594767f;
    float cn[NQ], sn[NQ];
    const float* xp = x + (size_t)(b0 + lane) * NQ;
    #pragma unroll
    for (int w = 0; w < NQ; ++w) {
        float h = xp[w] * RV;
        cn[w] = __builtin_amdgcn_cosf(h);
        sn[w] = __builtin_amdgcn_sinf(h);
    }
    float base[DIM];
    base[0] = cn[0]; base[1] = sn[0];
    #pragma unroll
    for (int w = 1; w < NQ; ++w) {
        #pragma unroll
        for (int j = (1 << w) - 1; j >= 0; --j) {
            float v = base[j];
            base[2*j + 1] = v * sn[w];
            base[2*j]     = v * cn[w];
        }
    }

    // ---- relay base -> B-fragment order (same-wave RAW; wave-private slice)
    #pragma unroll
    for (int q = 0; q < 8; ++q)
        relay[q * 64 + lane] = *(f32x4*)&base[q * 4];

    half8 BhF[4], BlF[4];
    #pragma unroll
    for (int tb = 0; tb < 4; ++tb) {
        f32x4 r0 = relay[(kg*2 + 0) * 64 + tb*16 + l15];
        f32x4 r1 = relay[(kg*2 + 1) * 64 + tb*16 + l15];
        float b8[8] = {r0[0], r0[1], r0[2], r0[3], r1[0], r1[1], r1[2], r1[3]};
        half8 h, lo;
        #pragma unroll
        for (int e = 0; e < 8; ++e) {
            _Float16 hh = (_Float16)b8[e];
            h[e]  = hh;
            lo[e] = (_Float16)(b8[e] - (float)hh);
        }
        BhF[tb] = h; BlF[tb] = lo;
    }

    // ---- main: FULLY UNROLLED tb x g (all register indices compile-time).
    // Per tb: 4 gens x 3 MFMA -> scaled p into swizzled stage -> 4 x 1KB
    // contiguous store instrs (full lines, L2 write-combined).
    f32x4* ob4 = (f32x4*)(out + (size_t)b0 * 64);
    #pragma unroll
    for (int tb = 0; tb < 4; ++tb) {
        #pragma unroll
        for (int g = 0; g < NG; ++g) {
            f32x4 acc = {0.f, 0.f, 0.f, 0.f};
            acc = __builtin_amdgcn_mfma_f32_16x16x32_f16(MhA[g], BhF[tb], acc, 0, 0, 0);
            acc = __builtin_amdgcn_mfma_f32_16x16x32_f16(MlA[g], BhF[tb], acc, 0, 0, 0);
            acc = __builtin_amdgcn_mfma_f32_16x16x32_f16(MhA[g], BlF[tb], acc, 0, 0, 0);
            // D layout (m89-verified): reg r = slot kg*4+r, col l15 = batch.
            float p0 = acc[0]*acc[0], p1 = acc[1]*acc[1];
            float p2 = acc[2]*acc[2], p3 = acc[3]*acc[3];
            float mx = fmaxf(fmaxf(p0, p1), fmaxf(p2, p3));
            mx = fmaxf(mx, __shfl_xor(mx, 16, 64));   // combine the 4 kg lanes
            mx = fmaxf(mx, __shfl_xor(mx, 32, 64));
            float inv = __builtin_amdgcn_rcpf(mx);
            // swizzled slab: [batch l15][f4-slot (g*4+kg) ^ l15]
            f32x4 v = {p0*inv, p1*inv, p2*inv, p3*inv};
            stage[l15 * 16 + ((g*4 + kg) ^ l15)] = v;
        }
        // drain: 4 KB contiguous (batches tb*16..tb*16+15, full 256-B rows)
        #pragma unroll
        for (int j = 0; j < 4; ++j) {
            int f  = lane + 64 * j;      // f4 index within the tb region
            int br = f >> 4;             // local batch 0..15
            int sl = f & 15;             // f4 slot within the row
            ob4[tb * 256 + f] = stage[br * 16 + (sl ^ br)];
        }
    }
}

extern "C" void kernel_launch(void* const* d_in, const int* in_sizes, int n_in,
                              void* d_out, int out_size, void* d_ws, size_t ws_size,
                              hipStream_t stream) {
    const float* x  = (const float*)d_in[0];
    const float* qp = (const float*)d_in[1];
    float* out = (float*)d_out;
    float* M = (float*)d_ws;               // 8 KB scratch
    const int B = in_sizes[0] / NQ;
    build_M<<<1, 128, 0, stream>>>(qp, M);
    qgen8<<<B / 256, 256, 0, stream>>>(x, M, out);
}

// Round 11
// 24.819 us; speedup vs baseline: 2.4429x; 1.0483x over previous
//
#include <hip/hip_runtime.h>

#define NQ 5
#define NL 6
#define NG 4
#define DIM 32
#define PATCH 16
#define MPITCH 33   // LDS row pitch for M: 33 floats -> <=2-way bank alias (free)

typedef _Float16 half8 __attribute__((ext_vector_type(8)));
typedef float f32x4 __attribute__((ext_vector_type(4)));

// CZ-chain sign: flip amplitude i iff # adjacent set-bit pairs is odd.
__device__ __forceinline__ int flip_par(int i) {
    int p = i & (i >> 1) & 0xF;
    p ^= p >> 2; p ^= p >> 1;
    return p & 1;
}

// Single fused kernel.
//  Phase A (all 256 thr): x load -> trig -> product state (lane = batch).
//  Phase B (t<128):       basis-column sim of the weight circuit -> M in LDS
//                         (thread (g,col) simulates e_col; verified R1-R10).
//  Phase C (all):         A-fragments from LDS M, f16 hi/lo split.
//  Phase D (all):         relay -> B-frags -> 16 tiles x 3 MFMA -> swizzled
//                         stage -> contiguous 1KB stores (verified R10).
// lmM (8.4 KB) overlays the wave-0/1 relay slabs; barriers 1+2 separate the
// lifetimes. LDS stays 32 KB -> 4 blocks/CU.
__global__ __launch_bounds__(256, 4) void qgen9(
        const float* __restrict__ x, const float* __restrict__ qp,
        float* __restrict__ out) {
    __shared__ __align__(16) f32x4 smem[4][512];   // 32 KB
    float* lmM = (float*)smem;                     // [64 rows][MPITCH] floats

    const int t = threadIdx.x;
    const int wid = t >> 6, lane = t & 63;
    const int l15 = lane & 15, kg = lane >> 4;
    const int b0 = (blockIdx.x * 4 + wid) * 64;

    // ---- Phase A: per-lane trig + product state (verified R1-R10)
    const float RV = 0.07957747154594767f; // 0.5/(2*pi): v_sin/v_cos take revolutions
    float cn[NQ], sn[NQ];
    const float* xp = x + (size_t)(b0 + lane) * NQ;
    #pragma unroll
    for (int w = 0; w < NQ; ++w) {
        float h = xp[w] * RV;
        cn[w] = __builtin_amdgcn_cosf(h);
        sn[w] = __builtin_amdgcn_sinf(h);
    }
    float base[DIM];
    base[0] = cn[0]; base[1] = sn[0];
    #pragma unroll
    for (int w = 1; w < NQ; ++w) {
        #pragma unroll
        for (int j = (1 << w) - 1; j >= 0; --j) {
            float v = base[j];
            base[2*j + 1] = v * sn[w];
            base[2*j]     = v * cn[w];
        }
    }

    // ---- Phase B: t<128 builds M into LDS (basis sim; same numerics as R10)
    if (t < 128) {
        const int g = t >> 5, col = t & 31;
        float st[DIM];
        #pragma unroll
        for (int i = 0; i < DIM; ++i) st[i] = (i == col) ? 1.0f : 0.0f;
        #pragma unroll          // full unroll: qp loads hoist & pipeline
        for (int l = 0; l < NL; ++l) {
            #pragma unroll
            for (int w = 0; w < NQ; ++w) {
                float h = qp[g*(NL*NQ) + l*NQ + w] * RV;
                float c = __builtin_amdgcn_cosf(h);
                float s = __builtin_amdgcn_sinf(h);
                const int bit = 4 - w, str = 1 << bit;
                #pragma unroll
                for (int p = 0; p < 16; ++p) {
                    int lo = ((p >> bit) << (bit + 1)) | (p & (str - 1));
                    int hi = lo + str;
                    float a0 = st[lo], a1 = st[hi];
                    st[lo] = c*a0 - s*a1;
                    st[hi] = s*a0 + c*a1;
                }
            }
            if (l != NL - 1) {  // outermost sign layer dies in |.|^2
                #pragma unroll
                for (int i = 0; i < DIM; ++i)
                    if (flip_par(i)) st[i] = -st[i];
            }
        }
        #pragma unroll
        for (int r = 0; r < PATCH; ++r)
            lmM[(g*PATCH + r)*MPITCH + col] = st[r];  // 2-way max: free
    }
    __syncthreads();   // barrier 1: lmM ready

    // ---- Phase C: A-fragments from LDS M (b32 reads, 2-way max), f16 split
    half8 MhA[NG], MlA[NG];
    #pragma unroll
    for (int g = 0; g < NG; ++g) {
        const float* mr = &lmM[(g*PATCH + l15)*MPITCH + kg*8];
        float m8[8];
        #pragma unroll
        for (int e = 0; e < 8; ++e) m8[e] = mr[e];
        half8 h, lo;
        #pragma unroll
        for (int e = 0; e < 8; ++e) {
            _Float16 hh = (_Float16)m8[e];
            h[e]  = hh;
            lo[e] = (_Float16)(m8[e] - (float)hh);
        }
        MhA[g] = h; MlA[g] = lo;
    }
    __syncthreads();   // barrier 2: lmM dead; relay may overwrite it

    // ---- Phase D: relay base -> B-frag order (same-wave RAW; wave-private)
    f32x4* relay = smem[wid];
    f32x4* stage = smem[wid];
    #pragma unroll
    for (int q = 0; q < 8; ++q)
        relay[q * 64 + lane] = *(f32x4*)&base[q * 4];

    half8 BhF[4], BlF[4];
    #pragma unroll
    for (int tb = 0; tb < 4; ++tb) {
        f32x4 r0 = relay[(kg*2 + 0) * 64 + tb*16 + l15];
        f32x4 r1 = relay[(kg*2 + 1) * 64 + tb*16 + l15];
        float b8[8] = {r0[0], r0[1], r0[2], r0[3], r1[0], r1[1], r1[2], r1[3]};
        half8 h, lo;
        #pragma unroll
        for (int e = 0; e < 8; ++e) {
            _Float16 hh = (_Float16)b8[e];
            h[e]  = hh;
            lo[e] = (_Float16)(b8[e] - (float)hh);
        }
        BhF[tb] = h; BlF[tb] = lo;
    }

    // ---- main: FULLY UNROLLED tb x g (rule #20: all reg indices static).
    // Per tb: 4 gens x 3 MFMA -> scaled p into swizzled stage -> 4 x 1KB
    // contiguous store instrs (full lines). Verified R10.
    f32x4* ob4 = (f32x4*)(out + (size_t)b0 * 64);
    #pragma unroll
    for (int tb = 0; tb < 4; ++tb) {
        #pragma unroll
        for (int g = 0; g < NG; ++g) {
            f32x4 acc = {0.f, 0.f, 0.f, 0.f};
            acc = __builtin_amdgcn_mfma_f32_16x16x32_f16(MhA[g], BhF[tb], acc, 0, 0, 0);
            acc = __builtin_amdgcn_mfma_f32_16x16x32_f16(MlA[g], BhF[tb], acc, 0, 0, 0);
            acc = __builtin_amdgcn_mfma_f32_16x16x32_f16(MhA[g], BlF[tb], acc, 0, 0, 0);
            // D layout (m89-verified): reg r = slot kg*4+r, col l15 = batch.
            float p0 = acc[0]*acc[0], p1 = acc[1]*acc[1];
            float p2 = acc[2]*acc[2], p3 = acc[3]*acc[3];
            float mx = fmaxf(fmaxf(p0, p1), fmaxf(p2, p3));
            mx = fmaxf(mx, __shfl_xor(mx, 16, 64));   // combine the 4 kg lanes
            mx = fmaxf(mx, __shfl_xor(mx, 32, 64));
            float inv = __builtin_amdgcn_rcpf(mx);
            // swizzled slab: [batch l15][f4-slot (g*4+kg) ^ l15]
            f32x4 v = {p0*inv, p1*inv, p2*inv, p3*inv};
            stage[l15 * 16 + ((g*4 + kg) ^ l15)] = v;
        }
        // drain: 4 KB contiguous (batches tb*16..tb*16+15, full 256-B rows)
        #pragma unroll
        for (int j = 0; j < 4; ++j) {
            int f  = lane + 64 * j;      // f4 index within the tb region
            int br = f >> 4;             // local batch 0..15
            int sl = f & 15;             // f4 slot within the row
            ob4[tb * 256 + f] = stage[br * 16 + (sl ^ br)];
        }
    }
}

extern "C" void kernel_launch(void* const* d_in, const int* in_sizes, int n_in,
                              void* d_out, int out_size, void* d_ws, size_t ws_size,
                              hipStream_t stream) {
    const float* x  = (const float*)d_in[0];
    const float* qp = (const float*)d_in[1];
    float* out = (float*)d_out;
    const int B = in_sizes[0] / NQ;
    qgen9<<<B / 256, 256, 0, stream>>>(x, qp, out);
}

// Round 13
// 24.406 us; speedup vs baseline: 2.4843x; 1.0169x over previous
//
#include <hip/hip_runtime.h>

#define NQ 5
#define NL 6
#define NG 4
#define DIM 32
#define PATCH 16

typedef _Float16 half8 __attribute__((ext_vector_type(8)));
typedef float f32x4 __attribute__((ext_vector_type(4)));

// CZ-chain sign: flip amplitude i iff # adjacent set-bit pairs is odd.
__device__ __forceinline__ int flip_par(int i) {
    int p = i & (i >> 1) & 0xF;
    p ^= p >> 2; p ^= p >> 1;
    return p & 1;
}

// Single fused kernel (R13 = R12 with lmM moved to a DEDICATED LDS region —
// no union with relay/stage; the only structural delta vs the R12 tripwire
// failure. Swizzled addressing keeps it 8 KB with <=2-way bank alias).
//  Phase A (all):   x load -> trig -> product state (lane = batch).
//  Phase B (one wave, wid == (blockIdx>>8)&3, SIMD-spread across the 4
//                   co-resident blocks): ADJOINT basis sim -> M rows in lmMs.
//                   Row r of M = U'^T e_r: loop l=5..0 apply RY(-theta),
//                   sign after each layer except l=0. Math verified R12
//                   (call-1 absmax passed).
//  Phase C (all):   A-fragments from lmMs, f16 hi/lo split.
//  Phase D (all):   relay -> B-frags -> 16 tiles x 3 MFMA -> swizzled stage
//                   -> contiguous 1KB stores (verified R10/R11).
// LDS: smem 32 KB (relay/stage per-wave union, same-wave ordered — verified
// R10/R11) + lmMs 8 KB dedicated = 40960 B exactly -> 4 blocks/CU.
__global__ __launch_bounds__(256, 4) void qgen11(
        const float* __restrict__ x, const float* __restrict__ qp,
        float* __restrict__ out) {
    __shared__ __align__(16) f32x4 smem[4][512];   // 32 KB relay/stage
    __shared__ float lmMs[64 * DIM];               // 8 KB dedicated M

    const int t = threadIdx.x;
    const int wid = t >> 6, lane = t & 63;
    const int l15 = lane & 15, kg = lane >> 4;
    const int b0 = (blockIdx.x * 4 + wid) * 64;

    // ---- Phase A: per-lane trig + product state (verified R1-R11)
    const float RV = 0.07957747154594767f; // 0.5/(2*pi): v_sin/v_cos take revolutions
    float cn[NQ], sn[NQ];
    const float* xp = x + (size_t)(b0 + lane) * NQ;
    #pragma unroll
    for (int w = 0; w < NQ; ++w) {
        float h = xp[w] * RV;
        cn[w] = __builtin_amdgcn_cosf(h);
        sn[w] = __builtin_amdgcn_sinf(h);
    }
    float base[DIM];
    base[0] = cn[0]; base[1] = sn[0];
    #pragma unroll
    for (int w = 1; w < NQ; ++w) {
        #pragma unroll
        for (int j = (1 << w) - 1; j >= 0; --j) {
            float v = base[j];
            base[2*j + 1] = v * sn[w];
            base[2*j]     = v * cn[w];
        }
    }

    // ---- Phase B: one SIMD-spread wave builds M rows via ADJOINT sim.
    // lane -> (g = lane>>4, r = lane&15); row index g*16+r == lane.
    if (wid == ((blockIdx.x >> 8) & 3)) {
        const int g = lane >> 4;           // for qp addressing
        const int r = lane & 15;
        float st[DIM];
        #pragma unroll
        for (int i = 0; i < DIM; ++i) st[i] = (i == r) ? 1.0f : 0.0f;
        #pragma unroll
        for (int l = NL - 1; l >= 0; --l) {
            #pragma unroll
            for (int w = 0; w < NQ; ++w) {
                float h = qp[g*(NL*NQ) + l*NQ + w] * RV;
                float c = __builtin_amdgcn_cosf(h);
                float s = __builtin_amdgcn_sinf(h);
                const int bit = 4 - w, str = 1 << bit;
                #pragma unroll
                for (int p = 0; p < 16; ++p) {
                    int lo = ((p >> bit) << (bit + 1)) | (p & (str - 1));
                    int hi = lo + str;
                    float a0 = st[lo], a1 = st[hi];
                    st[lo] = c*a0 + s*a1;      // RY(-theta): transpose of fwd
                    st[hi] = c*a1 - s*a0;
                }
            }
            if (l != 0) {       // sign after each adjoint layer except the last
                #pragma unroll
                for (int i = 0; i < DIM; ++i)
                    if (flip_par(i)) st[i] = -st[i];
            }
        }
        // swizzled write: bank (i+lane)&31 over 64 lanes = 2-way (free)
        #pragma unroll
        for (int i = 0; i < DIM; ++i)
            lmMs[(lane << 5) + ((i + lane) & 31)] = st[i];
    }
    __syncthreads();   // barrier 1: lmMs ready

    // ---- Phase C: A-fragments from lmMs (b32 reads, 2-way max), f16 split
    half8 MhA[NG], MlA[NG];
    #pragma unroll
    for (int g = 0; g < NG; ++g) {
        const int row = g * PATCH + l15;
        float m8[8];
        #pragma unroll
        for (int e = 0; e < 8; ++e)
            m8[e] = lmMs[(row << 5) + ((kg*8 + e + row) & 31)];
        half8 h, lo;
        #pragma unroll
        for (int e = 0; e < 8; ++e) {
            _Float16 hh = (_Float16)m8[e];
            h[e]  = hh;
            lo[e] = (_Float16)(m8[e] - (float)hh);
        }
        MhA[g] = h; MlA[g] = lo;
    }
    __syncthreads();   // barrier 2 (conservative; lmMs untouched hereafter)

    // ---- Phase D: relay base -> B-frag order (same-wave RAW; wave-private)
    f32x4* relay = smem[wid];
    f32x4* stage = smem[wid];
    #pragma unroll
    for (int q = 0; q < 8; ++q)
        relay[q * 64 + lane] = *(f32x4*)&base[q * 4];

    half8 BhF[4], BlF[4];
    #pragma unroll
    for (int tb = 0; tb < 4; ++tb) {
        f32x4 r0 = relay[(kg*2 + 0) * 64 + tb*16 + l15];
        f32x4 r1 = relay[(kg*2 + 1) * 64 + tb*16 + l15];
        float b8[8] = {r0[0], r0[1], r0[2], r0[3], r1[0], r1[1], r1[2], r1[3]};
        half8 h, lo;
        #pragma unroll
        for (int e = 0; e < 8; ++e) {
            _Float16 hh = (_Float16)b8[e];
            h[e]  = hh;
            lo[e] = (_Float16)(b8[e] - (float)hh);
        }
        BhF[tb] = h; BlF[tb] = lo;
    }

    // ---- main: FULLY UNROLLED tb x g (rule #20: all reg indices static).
    // Per tb: 4 gens x 3 MFMA -> scaled p into swizzled stage -> 4 x 1KB
    // contiguous store instrs (full lines). Verified R10/R11.
    f32x4* ob4 = (f32x4*)(out + (size_t)b0 * 64);
    #pragma unroll
    for (int tb = 0; tb < 4; ++tb) {
        #pragma unroll
        for (int g = 0; g < NG; ++g) {
            f32x4 acc = {0.f, 0.f, 0.f, 0.f};
            acc = __builtin_amdgcn_mfma_f32_16x16x32_f16(MhA[g], BhF[tb], acc, 0, 0, 0);
            acc = __builtin_amdgcn_mfma_f32_16x16x32_f16(MlA[g], BhF[tb], acc, 0, 0, 0);
            acc = __builtin_amdgcn_mfma_f32_16x16x32_f16(MhA[g], BlF[tb], acc, 0, 0, 0);
            // D layout (m89-verified): reg r = slot kg*4+r, col l15 = batch.
            float p0 = acc[0]*acc[0], p1 = acc[1]*acc[1];
            float p2 = acc[2]*acc[2], p3 = acc[3]*acc[3];
            float mx = fmaxf(fmaxf(p0, p1), fmaxf(p2, p3));
            mx = fmaxf(mx, __shfl_xor(mx, 16, 64));   // combine the 4 kg lanes
            mx = fmaxf(mx, __shfl_xor(mx, 32, 64));
            float inv = __builtin_amdgcn_rcpf(mx);
            // swizzled slab: [batch l15][f4-slot (g*4+kg) ^ l15]
            f32x4 v = {p0*inv, p1*inv, p2*inv, p3*inv};
            stage[l15 * 16 + ((g*4 + kg) ^ l15)] = v;
        }
        // drain: 4 KB contiguous (batches tb*16..tb*16+15, full 256-B rows)
        #pragma unroll
        for (int j = 0; j < 4; ++j) {
            int f  = lane + 64 * j;      // f4 index within the tb region
            int br = f >> 4;             // local batch 0..15
            int sl = f & 15;             // f4 slot within the row
            ob4[tb * 256 + f] = stage[br * 16 + (sl ^ br)];
        }
    }
}

extern "C" void kernel_launch(void* const* d_in, const int* in_sizes, int n_in,
                              void* d_out, int out_size, void* d_ws, size_t ws_size,
                              hipStream_t stream) {
    const float* x  = (const float*)d_in[0];
    const float* qp = (const float*)d_in[1];
    float* out = (float*)d_out;
    const int B = in_sizes[0] / NQ;
    qgen11<<<B / 256, 256, 0, stream>>>(x, qp, out);
}